// Round 6
// baseline (1016.461 us; speedup 1.0000x reference)
//
#include <hip/hip_runtime.h>
#include <stdint.h>

typedef __bf16 bf16;
typedef __attribute__((ext_vector_type(8))) __bf16 bf16x8;
typedef __attribute__((ext_vector_type(4))) float f32x4;
typedef unsigned short u16;
typedef unsigned int u32;

#define B_TOK 4096
#define D_IN  1024
#define D_HID 4096
#define D_OUT 1024
#define NE    8
#define KTOT  (NE * D_HID)   // 32768

#define AS1 __attribute__((address_space(1)))
#define AS3 __attribute__((address_space(3)))

// fp32 -> bf16 round-to-nearest-even
__device__ __forceinline__ u16 f2bf(float f) {
  u32 u = __float_as_uint(f);
  return (u16)((u + 0x7FFFu + ((u >> 16) & 1u)) >> 16);
}
__device__ __forceinline__ u32 pack2(float a, float b) {
  return (u32)f2bf(a) | ((u32)f2bf(b) << 16);
}

// ---------------- convert fp32 -> bf16 (contiguous) ----------------
__global__ __launch_bounds__(256) void cvt_bf16_kernel(const float* __restrict__ in,
                                                       u32* __restrict__ out, long n) {
  long i = ((long)blockIdx.x * 256 + threadIdx.x) * 8;
  if (i >= n) return;
  const float4* pf = (const float4*)(in + i);
  float4 f0 = pf[0], f1 = pf[1];
  uint4 o = make_uint4(pack2(f0.x, f0.y), pack2(f0.z, f0.w),
                       pack2(f1.x, f1.y), pack2(f1.z, f1.w));
  *(uint4*)(out + i / 2) = o;
}

// ------- batched transpose + convert: in[z][R][C] f32 -> out[z][C][R] bf16 -------
__global__ __launch_bounds__(256) void transpose_bf16_kernel(const float* __restrict__ in,
                                                             u16* __restrict__ out,
                                                             int R, int C) {
  __shared__ u16 tileT[64][68];   // [col-of-in][row-of-in]
  const size_t bo = (size_t)blockIdx.z * R * C;
  const int c0 = blockIdx.x * 64, r0 = blockIdx.y * 64;
  const int tid = threadIdx.x;
  const int lr = tid >> 4;           // 0..15
  const int lc = (tid & 15) * 4;     // 0..60
#pragma unroll
  for (int p = 0; p < 4; ++p) {
    const int r = p * 16 + lr;
    const float4 v = *(const float4*)(in + bo + (size_t)(r0 + r) * C + c0 + lc);
    tileT[lc + 0][r] = f2bf(v.x);
    tileT[lc + 1][r] = f2bf(v.y);
    tileT[lc + 2][r] = f2bf(v.z);
    tileT[lc + 3][r] = f2bf(v.w);
  }
  __syncthreads();
  const int oc  = tid >> 3;          // 0..31
  const int och = (tid & 7) * 8;     // 0..56
#pragma unroll
  for (int p = 0; p < 2; ++p) {
    const int c = p * 32 + oc;
    bf16x8 v = *(const bf16x8*)(&tileT[c][och]);
    *(bf16x8*)(out + bo + (size_t)(c0 + c) * R + r0 + och) = v;
  }
}

// ------- 256x128 MFMA GEMM, BK=64, 3-deep LDS pipeline, counted vmcnt -------
// C[m,n] (+)= sum_k A[m,k] * Bt[n,k]
// MODE 0: gating L1  : C = bf16( relu(acc + bias[n]) ),               grid (16,32,1)
// MODE 1: expert L1  : C = bf16( gate[m,e] * relu(acc + bias[e,n]) ), grid (16,32,E)
// MODE 2: final      : atomicAdd fp32 C += acc (split-K over z),      grid (16,8,4)
// 512 thr = 8 waves (2M x 4N), per-wave output 128x32, acc 8x2 f32x4 (64 VGPR).
// LDS 144 KB = 3 buffers x (A 256x64 | B 128x64) bf16 -> true 3-deep pipeline:
//   tile t top: vmcnt(6) waits tile-t loads (issued 2 tiles = ~4000cy earlier);
//   tile t+1's 6 loads STAY in flight across the wait (never drains in main loop);
//   barrier; issue 3 of tile t+2's loads; compute kh0; issue other 3; compute kh1.
// One barrier per K-tile. Hazards: bufs t,t+1,t+2 mod 3 distinct; WAR on
// buf((t+2)%3) ok because t-1's reads all completed before tile-t barrier.
// XOR swizzle (R2-verified ~0 conflicts): LDS chunk slot = global chunk ^ (row&7),
// folded into the staging lane->global map; ds_reads use the same involution.
template<int MODE>
__global__ __launch_bounds__(512, 2) void gemm_mfma256(
    const bf16* __restrict__ A,
    const bf16* __restrict__ Bt,
    const float* __restrict__ bias,
    const float* __restrict__ gate,
    void* __restrict__ Cptr,
    int K, long ldB, long kOffB, long ldC, int kIters, int eArg)
{
  __shared__ __align__(16) bf16 smem[3 * 24576];   // 144 KB

  const int tid  = threadIdx.x;
  const int wave = tid >> 6;
  const int lane = tid & 63;
  const int quad = lane >> 4;
  const int l16  = lane & 15;
  const int wr = (wave >> 2) * 128;   // wave row base (0 or 128)
  const int wc = (wave & 3) * 32;     // wave col base (0..96)

  const int m0 = blockIdx.x * 256;
  const int n0 = blockIdx.y * 128;

  int expert = 0;
  long cColOff = 0;
  const bf16* Bp = Bt;
  const float* biasP = bias;
  if (MODE == 1) {
    if (gridDim.z > 1) { expert = blockIdx.z; cColOff = (long)expert * D_HID; }
    else               { expert = eArg; }
    Bp = Bt + (size_t)expert * D_HID * (size_t)ldB;
    biasP = bias + (size_t)expert * D_HID;
  }
  const int nt = kIters;                                   // K-tiles of 64
  const long kBase = (MODE == 2) ? (long)blockIdx.z * nt * 64 : 0;

  // staging: each gload instr = 64 lanes x 16B = 8 rows x 128B (one 64-row group
  // per instr across 8 waves). lane -> row (lane>>3), LDS chunk lane&7;
  // global chunk = (lane&7) ^ (row&7).
  const int sRow = lane >> 3;                      // 0..7
  const int sCol = ((lane & 7) ^ sRow) * 8;        // pre-swizzled global k-chunk

  const bf16* aSrc = A  + (size_t)(m0 + wave * 8 + sRow) * K   + kBase + sCol;
  const bf16* bSrc = Bp + (size_t)(n0 + wave * 8 + sRow) * ldB + kOffB + kBase + sCol;

  f32x4 acc[8][2];
#pragma unroll
  for (int i = 0; i < 8; ++i)
#pragma unroll
    for (int j = 0; j < 2; ++j)
      acc[i][j] = (f32x4){0.f, 0.f, 0.f, 0.f};

  // stage instr s of tile tt into buffer bb. s=0..3 -> A row-groups 0..3;
  // s=4..5 -> B row-groups 0..1.
#define GST(tt, bb, s) do { \
    if ((s) < 4) { \
      __builtin_amdgcn_global_load_lds( \
        (AS1 void*)(aSrc + (size_t)(tt) * 64 + (size_t)(s) * 64 * K), \
        (AS3 void*)(smem + (bb) * 24576 + (s) * 4096 + wave * 512), 16, 0, 0); \
    } else { \
      __builtin_amdgcn_global_load_lds( \
        (AS1 void*)(bSrc + (size_t)(tt) * 64 + (size_t)((s) - 4) * 64 * ldB), \
        (AS3 void*)(smem + (bb) * 24576 + 16384 + ((s) - 4) * 4096 + wave * 512), 16, 0, 0); \
    } \
  } while (0)

#define TILE_BODY(T, VMW, ISS) do { \
    const bf16* Ab_ = smem + ((T) % 3) * 24576; \
    const bf16* Bb_ = Ab_ + 16384; \
    asm volatile("s_waitcnt vmcnt(" #VMW ")" ::: "memory"); \
    __builtin_amdgcn_s_barrier(); \
    __builtin_amdgcn_sched_barrier(0); \
    if (ISS) { GST((T) + 2, ((T) + 2) % 3, 0); GST((T) + 2, ((T) + 2) % 3, 1); \
               GST((T) + 2, ((T) + 2) % 3, 2); } \
    _Pragma("unroll") \
    for (int kh_ = 0; kh_ < 2; ++kh_) { \
      const int sw_ = (((kh_ << 2) + quad) ^ (l16 & 7)) << 3; \
      bf16x8 bv_[2], av_[8]; \
      _Pragma("unroll") \
      for (int j_ = 0; j_ < 2; ++j_) \
        bv_[j_] = *(const bf16x8*)(Bb_ + (wc + j_ * 16 + l16) * 64 + sw_); \
      _Pragma("unroll") \
      for (int i_ = 0; i_ < 8; ++i_) \
        av_[i_] = *(const bf16x8*)(Ab_ + (wr + i_ * 16 + l16) * 64 + sw_); \
      __builtin_amdgcn_s_setprio(1); \
      _Pragma("unroll") \
      for (int i_ = 0; i_ < 8; ++i_) \
        _Pragma("unroll") \
        for (int j_ = 0; j_ < 2; ++j_) \
          acc[i_][j_] = __builtin_amdgcn_mfma_f32_16x16x32_bf16(av_[i_], bv_[j_], acc[i_][j_], 0, 0, 0); \
      __builtin_amdgcn_s_setprio(0); \
      if (kh_ == 0 && (ISS)) { GST((T) + 2, ((T) + 2) % 3, 3); \
                               GST((T) + 2, ((T) + 2) % 3, 4); \
                               GST((T) + 2, ((T) + 2) % 3, 5); } \
    } \
  } while (0)

  // prologue: stage tiles 0 and 1 (12 loads in flight)
#pragma unroll
  for (int s = 0; s < 6; ++s) GST(0, 0, s);
#pragma unroll
  for (int s = 0; s < 6; ++s) GST(1, 1, s);

  for (int t = 0; t < nt - 1; ++t) TILE_BODY(t, 6, (t < nt - 2));
  TILE_BODY(nt - 1, 0, 0);

#undef GST
#undef TILE_BODY

  // epilogue: C/D layout col = lane&15, row = quad*4 + reg
  if (MODE <= 1) {
    const int SL = 40;
    u16* slab = (u16*)smem + wave * (16 * SL);
    u16* C = (u16*)Cptr;
    __builtin_amdgcn_s_barrier();
    float bv[2];
#pragma unroll
    for (int j = 0; j < 2; ++j) bv[j] = biasP[n0 + wc + j * 16 + l16];
#pragma unroll
    for (int i = 0; i < 8; ++i) {
#pragma unroll
      for (int r = 0; r < 4; ++r) {
        const int lrow = quad * 4 + r;
        float sc = 1.0f;
        if (MODE == 1) sc = gate[(size_t)(m0 + wr + i * 16 + lrow) * NE + expert];
#pragma unroll
        for (int j = 0; j < 2; ++j) {
          float v = fmaxf(acc[i][j][r] + bv[j], 0.0f) * sc;
          slab[lrow * SL + j * 16 + l16] = f2bf(v);
        }
      }
      const int rrow = lane & 15;
      const int chk  = lane >> 4;    // 0..3 -> 8-col chunk
      bf16x8 v0 = *(const bf16x8*)(slab + rrow * SL + chk * 8);
      u16* orow = C + (size_t)(m0 + wr + i * 16 + rrow) * ldC + cColOff + n0 + wc;
      *(bf16x8*)(orow + chk * 8) = v0;
    }
  } else {
    float* C = (float*)Cptr;
#pragma unroll
    for (int i = 0; i < 8; ++i) {
#pragma unroll
      for (int r = 0; r < 4; ++r) {
        const int row = m0 + wr + i * 16 + quad * 4 + r;
        float* crow = C + (size_t)row * ldC + n0 + wc + l16;
#pragma unroll
        for (int j = 0; j < 2; ++j)
          atomicAdd(crow + j * 16, acc[i][j][r]);
      }
    }
  }
}

// ---------------- gating layer 2 + softmax: one wave per row ----------------
__global__ __launch_bounds__(256) void gate_softmax_kernel(const bf16* __restrict__ g,
                                                           const float* __restrict__ Wg2,
                                                           const float* __restrict__ bg2,
                                                           float* __restrict__ gate) {
  const int wave = threadIdx.x >> 6, lane = threadIdx.x & 63;
  const int row = blockIdx.x * 4 + wave;
  const bf16* gr = g + (size_t)row * D_HID;
  float acc[NE];
#pragma unroll
  for (int e = 0; e < NE; ++e) acc[e] = 0.f;
  for (int k = lane; k < D_HID; k += 64) {
    const float gv = (float)gr[k];
    const float* w = Wg2 + (size_t)k * NE;
#pragma unroll
    for (int e = 0; e < NE; ++e) acc[e] += gv * w[e];
  }
#pragma unroll
  for (int e = 0; e < NE; ++e) {
    float v = acc[e];
#pragma unroll
    for (int off = 32; off > 0; off >>= 1) v += __shfl_down(v, off);
    acc[e] = v;
  }
  if (lane == 0) {
    float mx = -3.4e38f;
#pragma unroll
    for (int e = 0; e < NE; ++e) { acc[e] += bg2[e]; mx = fmaxf(mx, acc[e]); }
    float s = 0.f;
#pragma unroll
    for (int e = 0; e < NE; ++e) { acc[e] = __expf(acc[e] - mx); s += acc[e]; }
    const float inv = 1.f / s;
#pragma unroll
    for (int e = 0; e < NE; ++e) gate[(size_t)row * NE + e] = acc[e] * inv;
  }
}

// ---------------- out = sum_e gate[b,e] * b2[e,o]  (WRITES out) -------------
__global__ __launch_bounds__(256) void gate_bias_kernel(const float* __restrict__ gate,
                                                        const float* __restrict__ b2,
                                                        float* __restrict__ out) {
  const int idx = blockIdx.x * 256 + threadIdx.x;
  const int b = idx >> 8;
  const int o = (idx & 255) * 4;
  float4 v = {0.f, 0.f, 0.f, 0.f};
#pragma unroll
  for (int e = 0; e < NE; ++e) {
    const float gv = gate[(size_t)b * NE + e];
    const float4 bb = *(const float4*)(b2 + (size_t)e * D_OUT + o);
    v.x += gv * bb.x; v.y += gv * bb.y; v.z += gv * bb.z; v.w += gv * bb.w;
  }
  *(float4*)(out + (size_t)b * D_OUT + o) = v;
}

extern "C" void kernel_launch(void* const* d_in, const int* in_sizes, int n_in,
                              void* d_out, int out_size, void* d_ws, size_t ws_size,
                              hipStream_t stream) {
  const float* x   = (const float*)d_in[0];   // [4096,1024]
  const float* W1  = (const float*)d_in[1];   // [8,1024,4096]
  const float* b1  = (const float*)d_in[2];   // [8,4096]
  const float* W2  = (const float*)d_in[3];   // [8,4096,1024] == [32768,1024]
  const float* b2  = (const float*)d_in[4];   // [8,1024]
  const float* Wg1 = (const float*)d_in[5];   // [1024,4096]
  const float* bg1 = (const float*)d_in[6];   // [4096]
  const float* Wg2 = (const float*)d_in[7];   // [4096,8]
  const float* bg2 = (const float*)d_in[8];   // [8]
  float* out = (float*)d_out;                 // [4096,1024] fp32

  char* p = (char*)d_ws;
  bf16* xb   = (bf16*)p; p += (size_t)B_TOK * D_IN * 2;        //  8.4 MB
  bf16* Wg1t = (bf16*)p; p += (size_t)D_HID * D_IN * 2;        //  8.4 MB [4096,1024]
  bf16* W1t  = (bf16*)p; p += (size_t)NE * D_HID * D_IN * 2;   // 67 MB   [8][4096,1024]
  bf16* W2t  = (bf16*)p; p += (size_t)D_OUT * KTOT * 2;        // 67 MB   [1024,32768]
  bf16* g    = (bf16*)p; p += (size_t)B_TOK * D_HID * 2;       // 33.5 MB
  float* gate= (float*)p; p += (size_t)B_TOK * NE * 4;         //  0.13 MB
  bf16* hs   = (bf16*)p;                                       // big: 268 MB / small: 33.5 MB
  const size_t fixed = (size_t)(p - (char*)d_ws);
  const bool big = ws_size >= fixed + (size_t)B_TOK * KTOT * 2;

  // 1. convert x to bf16
  cvt_bf16_kernel<<<(B_TOK * D_IN / 8 + 255) / 256, 256, 0, stream>>>(x, (u32*)xb, (long)B_TOK * D_IN);
  // 2. transpose+convert weights to [N,K] bf16 (64x64 tiles)
  transpose_bf16_kernel<<<dim3(D_HID / 64, D_IN / 64, 1), 256, 0, stream>>>(Wg1, (u16*)Wg1t, D_IN, D_HID);
  transpose_bf16_kernel<<<dim3(D_HID / 64, D_IN / 64, NE), 256, 0, stream>>>(W1, (u16*)W1t, D_IN, D_HID);
  transpose_bf16_kernel<<<dim3(D_OUT / 64, KTOT / 64, 1), 256, 0, stream>>>(W2, (u16*)W2t, KTOT, D_OUT);
  // 3. gating L1: g = relu(xb @ Wg1t^T + bg1)   M=4096 N=4096 K=1024
  gemm_mfma256<0><<<dim3(16, 32, 1), 512, 0, stream>>>(xb, Wg1t, bg1, nullptr, g,
                                                       D_IN, (long)D_IN, 0L, (long)D_HID, D_IN / 64, 0);
  // 4. gate = softmax(g @ Wg2 + bg2)
  gate_softmax_kernel<<<B_TOK / 4, 256, 0, stream>>>(g, Wg2, bg2, gate);
  // 5. out = sum_e gate*b2
  gate_bias_kernel<<<B_TOK * D_OUT / 4 / 256, 256, 0, stream>>>(gate, b2, out);

  if (big) {
    // 6. hs[b, e*4096+j] = gate[b,e]*relu(xb @ W1t[e]^T + b1[e])  grid 4096:
    //    default order -> each 512-block round = one expert (25 MB working set)
    gemm_mfma256<1><<<dim3(16, 32, NE), 512, 0, stream>>>(xb, W1t, b1, gate, hs,
                                                          D_IN, (long)D_IN, 0L, (long)KTOT, D_IN / 64, 0);
    // 7. out += hs @ W2flat   M=4096 N=1024 K=32768, split-K=4: grid 512 = 2 rounds
    gemm_mfma256<2><<<dim3(16, 8, 4), 512, 0, stream>>>(hs, W2t, nullptr, nullptr, out,
                                                        KTOT, (long)KTOT, 0L, (long)D_OUT, KTOT / 4 / 64, 0);
  } else {
    for (int e = 0; e < NE; ++e) {
      gemm_mfma256<1><<<dim3(16, 32, 1), 512, 0, stream>>>(xb, W1t, b1, gate, hs,
                                                           D_IN, (long)D_IN, 0L, (long)D_HID, D_IN / 64, e);
      gemm_mfma256<2><<<dim3(16, 8, 2), 512, 0, stream>>>(hs, W2t, nullptr, nullptr, out,
                                                          D_HID, (long)KTOT, (long)e * D_HID, (long)D_OUT,
                                                          D_HID / 2 / 64, e);
    }
  }
}